// Round 4
// baseline (281.754 us; speedup 1.0000x reference)
//
#include <hip/hip_runtime.h>
#include <hip/hip_bf16.h>

#define L_SEQ 4096
#define NH 8
#define DH 128
#define NQB 32
#define NKB 64
#define TOPK 32
#define KVCH 64   // kv partial chunks per head (64 rows each) == blockIdx.x of fused prep

typedef __bf16 bf16x8 __attribute__((ext_vector_type(8)));
typedef __bf16 bf16x4 __attribute__((ext_vector_type(4)));
typedef float floatx4 __attribute__((ext_vector_type(4)));

static_assert(sizeof(bf16x8) == 16, "bf16x8 must be 16B");
static_assert(sizeof(bf16x4) == 8, "bf16x4 must be 8B");

// ---------------- fused prep: K->bf16 [h][l][d]; V->bf16 transposed [h][d][l]; pks;
// ----------------             feature-map softmax(K) and kv outer-product partials.
__global__ __launch_bounds__(256) void k_prep(const float* __restrict__ kin,
                                              const float* __restrict__ vin,
                                              __bf16* __restrict__ kb,
                                              __bf16* __restrict__ vt,
                                              float* __restrict__ pks,
                                              float* __restrict__ kvp,
                                              float* __restrict__ ksp)
{
    __shared__ float kt[64][132];
    __shared__ float vtile[64][132];
    const int lb = blockIdx.x, h = blockIdx.y, t = threadIdx.x;
    const int r = t >> 2, seg = (t & 3) * 32;

    {   // stage K,V fp32 tiles; write K bf16 [h][l][d] from registers
        const float* ks = kin + ((long)((lb * 64 + r) * NH + h)) * DH + seg;
        const float* vs = vin + ((long)((lb * 64 + r) * NH + h)) * DH + seg;
        float frK[32];
#pragma unroll
        for (int j = 0; j < 8; ++j) {
            float4 a = ((const float4*)ks)[j];
            float4 b = ((const float4*)vs)[j];
            float* kd = &kt[r][seg + 4 * j];
            float* vd = &vtile[r][seg + 4 * j];
            kd[0] = a.x; kd[1] = a.y; kd[2] = a.z; kd[3] = a.w;
            vd[0] = b.x; vd[1] = b.y; vd[2] = b.z; vd[3] = b.w;
            frK[4 * j] = a.x; frK[4 * j + 1] = a.y; frK[4 * j + 2] = a.z; frK[4 * j + 3] = a.w;
        }
        bf16x8* kdst = (bf16x8*)(kb + ((long)(h * L_SEQ + lb * 64 + r)) * DH + seg);
#pragma unroll
        for (int g = 0; g < 4; ++g) {
            bf16x8 o;
#pragma unroll
            for (int e = 0; e < 8; ++e) o[e] = (__bf16)frK[g * 8 + e];
            kdst[g] = o;
        }
    }
    __syncthreads();
    if (t < 128) {   // K block column-sums -> pks (reads RAW kt, before softmax)
        float s = 0.f;
#pragma unroll 8
        for (int rr = 0; rr < 64; ++rr) s += kt[rr][t];
        pks[((long)(h * NKB + lb)) * DH + t] = s;
    }
    {   // V transpose -> vt16 [h][d][l] (vtile is never modified below)
        const int d = t >> 1, lh2 = (t & 1) * 32;
        bf16x8 ov[4];
#pragma unroll
        for (int i = 0; i < 32; ++i) ov[i >> 3][i & 7] = (__bf16)vtile[lh2 + i][d];
        bf16x8* dst = (bf16x8*)(vt + ((long)(h * DH + d)) * L_SEQ + lb * 64 + lh2);
#pragma unroll
        for (int j = 0; j < 4; ++j) dst[j] = ov[j];
    }
    __syncthreads();   // pks column reads must complete before in-place softmax

    {   // feature-map softmax over D, in place on kt: 4 threads/row, 32 cols each
        float vals[32];
        float* fr = &kt[r][seg];
#pragma unroll
        for (int j = 0; j < 8; ++j) {
            float4 x = ((const float4*)fr)[j];
            vals[4*j] = x.x; vals[4*j+1] = x.y; vals[4*j+2] = x.z; vals[4*j+3] = x.w;
        }
        float mx = -__builtin_inff();
#pragma unroll
        for (int c = 0; c < 32; ++c) mx = fmaxf(mx, vals[c]);
        mx = fmaxf(mx, __shfl_xor(mx, 1));
        mx = fmaxf(mx, __shfl_xor(mx, 2));
        float sm = 0.f;
#pragma unroll
        for (int c = 0; c < 32; ++c) { vals[c] = __expf(vals[c] - mx); sm += vals[c]; }
        sm += __shfl_xor(sm, 1);
        sm += __shfl_xor(sm, 2);
        const float inv = 1.f / sm;
#pragma unroll
        for (int j = 0; j < 8; ++j) {
            float4 x = {vals[4*j] * inv, vals[4*j+1] * inv, vals[4*j+2] * inv, vals[4*j+3] * inv};
            ((float4*)fr)[j] = x;
        }
    }
    __syncthreads();

    {   // kv outer-product partials: fk^T @ V over the 64 staged rows
        const int ci = t & 15, di = t >> 4;
        float acc[8][8];
#pragma unroll
        for (int i = 0; i < 8; ++i)
#pragma unroll
            for (int j = 0; j < 8; ++j) acc[i][j] = 0.f;
        float ks8[8] = {0.f, 0.f, 0.f, 0.f, 0.f, 0.f, 0.f, 0.f};
        for (int l = 0; l < 64; ++l) {
            float4 a0 = *(const float4*)&kt[l][ci * 8];
            float4 a1 = *(const float4*)&kt[l][ci * 8 + 4];
            float4 b0 = *(const float4*)&vtile[l][di * 8];
            float4 b1 = *(const float4*)&vtile[l][di * 8 + 4];
            float av[8] = {a0.x, a0.y, a0.z, a0.w, a1.x, a1.y, a1.z, a1.w};
            float bv[8] = {b0.x, b0.y, b0.z, b0.w, b1.x, b1.y, b1.z, b1.w};
#pragma unroll
            for (int i = 0; i < 8; ++i)
#pragma unroll
                for (int j = 0; j < 8; ++j) acc[i][j] += av[i] * bv[j];
            if (di == 0) {
#pragma unroll
                for (int i = 0; i < 8; ++i) ks8[i] += av[i];
            }
        }
        float* dst = kvp + (((long)(h * KVCH + lb) * 128) + ci * 8) * 128 + di * 8;
#pragma unroll
        for (int i = 0; i < 8; ++i) {
            float4 w0 = {acc[i][0], acc[i][1], acc[i][2], acc[i][3]};
            float4 w1 = {acc[i][4], acc[i][5], acc[i][6], acc[i][7]};
            ((float4*)(dst + (long)i * 128))[0] = w0;
            ((float4*)(dst + (long)i * 128))[1] = w1;
        }
        if (di == 0) {
            float* kd2 = ksp + (h * KVCH + lb) * 128 + ci * 8;
#pragma unroll
            for (int i = 0; i < 8; ++i) kd2[i] = ks8[i];
        }
    }
}

// ---------------- routing (fused Q-pool): rank-based top-32 ----------------
__global__ __launch_bounds__(256) void k_route(const float* __restrict__ q,
                                               const float* __restrict__ pks,
                                               int* __restrict__ lut)
{
    __shared__ float qv[128];
    __shared__ float qv2[128];
    __shared__ float sc[64];
    const int qi = blockIdx.x, h = blockIdx.y, t = threadIdx.x;
    {
        const int d = t & 127, half = t >> 7;
        float acc = 0.f;
        const int r0 = half * 64;
#pragma unroll 4
        for (int r = 0; r < 64; ++r)
            acc += q[((long)((qi * 128 + r0 + r) * NH + h)) * DH + d];
        if (half == 0) qv[d] = acc; else qv2[d] = acc;
    }
    __syncthreads();
    if (t < 128) qv[t] += qv2[t];
    __syncthreads();
    if (t < 64) {
        const float4* pr = (const float4*)(pks + ((long)(h * NKB + t)) * DH);
        const float4* qp = (const float4*)qv;
        float s = 0.f;
#pragma unroll 8
        for (int d4 = 0; d4 < 32; ++d4) {
            float4 a = qp[d4], b = pr[d4];
            s += a.x * b.x + a.y * b.y + a.z * b.z + a.w * b.w;
        }
        sc[t] = s;
    }
    __syncthreads();
    if (t < 64) {
        const float s = sc[t];
        int rank = 0;
        for (int j2 = 0; j2 < 64; ++j2) {
            float o = sc[j2];
            rank += (o > s) || (o == s && j2 < t);
        }
        if (rank < TOPK) lut[(h * NQB + qi) * TOPK + rank] = t;
    }
}

// ---------------- reduce partials; Mt[h][e][c] = (kv @ W^T)^T in bf16; ksum ----------------
__global__ __launch_bounds__(128) void k_reduce_m(const float* __restrict__ kvp,
                                                  const float* __restrict__ ksp,
                                                  const float* __restrict__ w,
                                                  __bf16* __restrict__ Mt,
                                                  float* __restrict__ ksum)
{
    __shared__ float wt[128][129];   // [d][e]
    __shared__ float kvr[4][128];
    __shared__ float shks[4][64];
    const int cb = blockIdx.x, h = blockIdx.y, t = threadIdx.x;
    const int c0 = cb * 4;
    {   // W transpose: coalesced loads, 2-way-free LDS writes
#pragma unroll 8
        for (int e = 0; e < 128; ++e) wt[t][e] = w[(long)e * DH + t];
    }
    {   // reduce kv partials for 4 c-rows
#pragma unroll
        for (int r = 0; r < 4; ++r) {
            float acc = 0.f;
            for (int ch = 0; ch < KVCH; ++ch)
                acc += kvp[(((long)(h * KVCH + ch) * 128) + c0 + r) * 128 + t];
            kvr[r][t] = acc;
        }
    }
    for (int i = t; i < 256; i += 128) {   // ksum partial stage
        const int r = i >> 6, ch = i & 63;
        shks[r][ch] = ksp[(h * KVCH + ch) * 128 + c0 + r];
    }
    __syncthreads();
    if (t < 4) {
        float s = 0.f;
#pragma unroll
        for (int ch = 0; ch < 64; ++ch) s += shks[t][ch];
        ksum[h * 128 + c0 + t] = s;
    }
    float m[4] = {0.f, 0.f, 0.f, 0.f};
#pragma unroll 4
    for (int d = 0; d < 128; ++d) {
        const float wv = wt[d][t];
#pragma unroll
        for (int r = 0; r < 4; ++r) m[r] += kvr[r][d] * wv;
    }
    // lane t owns Mt[e=t][c0..c0+3] -> one 8B store
    bf16x4 pk;
#pragma unroll
    for (int r = 0; r < 4; ++r) pk[r] = (__bf16)m[r];
    *(bf16x4*)(Mt + ((long)(h * 128 + t)) * 128 + c0) = pk;
}

// ---------------- linear apply (MFMA) + sparse merge: writes d_out, runs LAST ----------------
__global__ __launch_bounds__(256) void k_linear(const float* __restrict__ q,
                                                const __bf16* __restrict__ Mt,
                                                const float* __restrict__ ksum,
                                                const float* __restrict__ bproj,
                                                const float* __restrict__ Osp,
                                                const float* __restrict__ lsp,
                                                float* __restrict__ out)
{
    __shared__ __align__(16) __bf16 fq[128 * 136];   // raw exp, stride 136
    __shared__ float dinv[128];
    __shared__ float dsp[128];
    const int qb = blockIdx.x, h = blockIdx.y, t = threadIdx.x;
    const int l0 = qb * 128;

    {   // phase 1: per-row raw-exp + fused denominator; 2 threads/row
        const int row = t >> 1, half = t & 1;
        const float* qrow = q + ((long)((l0 + row) * NH + h)) * DH + half * 64;
        float vals[64];
#pragma unroll
        for (int j = 0; j < 16; ++j) {
            float4 x = ((const float4*)qrow)[j];
            vals[4*j] = x.x; vals[4*j+1] = x.y; vals[4*j+2] = x.z; vals[4*j+3] = x.w;
        }
        float mx = -__builtin_inff();
#pragma unroll
        for (int c = 0; c < 64; ++c) mx = fmaxf(mx, vals[c]);
        mx = fmaxf(mx, __shfl_xor(mx, 1));
        float sm = 0.f, dk = 0.f;
        const float* ks = ksum + h * DH + half * 64;
#pragma unroll
        for (int c = 0; c < 64; ++c) {
            float e = __expf(vals[c] - mx);
            vals[c] = e; sm += e; dk += e * ks[c];
        }
        __bf16* dst = fq + row * 136 + half * 64;
#pragma unroll
        for (int g = 0; g < 8; ++g) {
            bf16x8 o;
#pragma unroll
            for (int e2 = 0; e2 < 8; ++e2) o[e2] = (__bf16)vals[g * 8 + e2];
            *(bf16x8*)(dst + g * 8) = o;
        }
        sm += __shfl_xor(sm, 1);
        dk += __shfl_xor(dk, 1);
        if (half == 0) dinv[row] = 1.f / (1e-5f * sm + dk);
    }
    if (t < 128) {
        const long p0 = ((long)(h * NQB + qb)) * 128 + t;
        const long p1 = ((long)((NH + h) * NQB + qb)) * 128 + t;
        dsp[t] = 1.f / (lsp[p0] + lsp[p1]);
    }
    __syncthreads();

    // phase 2: MFMA  [128 rows x 128 e], wave w owns rows w*32..+32
    const int w = t >> 6, lane = t & 63, l16 = lane & 15, quad = lane >> 4;
    const __bf16* Bh = Mt + (long)h * DH * DH;
    const floatx4 vzero = {0.f, 0.f, 0.f, 0.f};
    floatx4 acc[2][8];
#pragma unroll
    for (int mt = 0; mt < 2; ++mt)
#pragma unroll
        for (int nt = 0; nt < 8; ++nt) acc[mt][nt] = vzero;
#pragma unroll
    for (int ksx = 0; ksx < 4; ++ksx) {
        bf16x8 af[2];
#pragma unroll
        for (int mt = 0; mt < 2; ++mt)
            af[mt] = *(const bf16x8*)(fq + (w * 32 + mt * 16 + l16) * 136 + ksx * 32 + quad * 8);
#pragma unroll
        for (int nt = 0; nt < 8; ++nt) {
            bf16x8 bf = *(const bf16x8*)(Bh + ((long)(nt * 16 + l16)) * DH + ksx * 32 + quad * 8);
#pragma unroll
            for (int mt = 0; mt < 2; ++mt)
                acc[mt][nt] = __builtin_amdgcn_mfma_f32_16x16x32_bf16(af[mt], bf, acc[mt][nt], 0, 0, 0);
        }
    }

    // epilogue: denom, bias, sparse merge
    float bias[8];
#pragma unroll
    for (int nt = 0; nt < 8; ++nt) bias[nt] = bproj[nt * 16 + l16];
    const float* O0b = Osp + (((long)(h * NQB + qb)) * 128) * 128;
    const float* O1b = Osp + (((long)((NH + h) * NQB + qb)) * 128) * 128;
#pragma unroll
    for (int mt = 0; mt < 2; ++mt) {
#pragma unroll
        for (int r = 0; r < 4; ++r) {
            const int row = w * 32 + mt * 16 + quad * 4 + r;
            const float di = dinv[row], ds = dsp[row];
            float* op = out + ((long)((l0 + row) * NH + h)) * DH;
            const float* o0 = O0b + (long)row * 128;
            const float* o1 = O1b + (long)row * 128;
#pragma unroll
            for (int nt = 0; nt < 8; ++nt) {
                const int e = nt * 16 + l16;
                op[e] = acc[mt][nt][r] * di + bias[nt] + (o0[e] + o1[e]) * ds;
            }
        }
    }
}

// ---------------- sparse flash attention v3: barrier-free, LDS-free main loop.
// ---------------- K/V MFMA fragments read DIRECTLY from global (L2-resident per XCD:
// ---------------- each head's K+V = 2 MB bf16, XCD swizzle pins head -> XCD).
// ---------------- Swapped QK^T + register-P transpose (verified r3). Waves free-run:
// ---------------- no phase convoy, MFMA/VALU/VMEM overlap across drifted waves.
static __device__ __forceinline__ unsigned int pack_bf16x2(float lo, float hi)
{
    union { __bf16 h[2]; unsigned int u; } cv;
    cv.h[0] = (__bf16)lo; cv.h[1] = (__bf16)hi;
    return cv.u;
}

__global__ __launch_bounds__(256, 2) void k_sparse(const float* __restrict__ q,
                                                   const __bf16* __restrict__ kb16,
                                                   const __bf16* __restrict__ vt16,
                                                   const int* __restrict__ lut,
                                                   float* __restrict__ Osp,
                                                   float* __restrict__ lsp)
{
    __shared__ int luts[16];

    const int id = blockIdx.x;
    const int xcd = id & 7, slot = id >> 3;
    const int pair = xcd + 8 * (slot >> 5);   // 0..15
    const int qb = slot & 31;
    const int h = pair >> 1, kc = pair & 1;
    const int t = threadIdx.x;
    const int w = t >> 6;
    const int lane = t & 63;
    const int l16 = lane & 15;
    const int quad = lane >> 4;
    const bool qe = (quad & 1) == 0;          // quad even?

    if (t < 16) luts[t] = lut[(h * NQB + qb) * TOPK + kc * 16 + t];

    bf16x8 qf[2][4];
#pragma unroll
    for (int mt = 0; mt < 2; ++mt) {
        const int gl = qb * 128 + w * 32 + mt * 16 + l16;
        const float* qrow = q + ((long)(gl * NH + h)) * DH;
#pragma unroll
        for (int ks = 0; ks < 4; ++ks) {
            const float4* s2 = (const float4*)(qrow + ks * 32 + quad * 8);
            float4 a = s2[0], b = s2[1];
            bf16x8 f;
            f[0] = (__bf16)a.x; f[1] = (__bf16)a.y; f[2] = (__bf16)a.z; f[3] = (__bf16)a.w;
            f[4] = (__bf16)b.x; f[5] = (__bf16)b.y; f[6] = (__bf16)b.z; f[7] = (__bf16)b.w;
            qf[mt][ks] = f;
        }
    }

    const floatx4 vzero = {0.f, 0.f, 0.f, 0.f};
    floatx4 o_acc[2][8];
#pragma unroll
    for (int mt = 0; mt < 2; ++mt)
#pragma unroll
        for (int nt = 0; nt < 8; ++nt) o_acc[mt][nt] = vzero;
    float lsum2[2] = {0.f, 0.f};

    const float scale = 0.08838834764831845f;
    const __bf16* kbh = kb16 + (long)h * L_SEQ * DH;
    const __bf16* vth = vt16 + (long)h * DH * L_SEQ + quad * 8;   // lane-const col part

    __syncthreads();   // luts ready — the ONLY barrier

    for (int it = 0; it < 16; ++it) {
        const int b0 = luts[it];
        const __bf16* kbb = kbh + (long)b0 * 64 * DH + quad * 8;
        const __bf16* vbb = vth + b0 * 64;

        // K fragments direct from global: kf[ks][nt] = K[b0*64 + nt*16+l16][ks*32+quad*8..+7]
        bf16x8 kf[4][4];
#pragma unroll
        for (int ks = 0; ks < 4; ++ks)
#pragma unroll
            for (int nt = 0; nt < 4; ++nt)
                kf[ks][nt] = *(const bf16x8*)(kbb + (long)(nt * 16 + l16) * DH + ks * 32);

        // swapped QK^T: sfr[mt][nt][r] = S[q = mt*16 + l16][k = nt*16 + quad*4 + r]
        floatx4 sfr[2][4];
#pragma unroll
        for (int mt = 0; mt < 2; ++mt)
#pragma unroll
            for (int nt = 0; nt < 4; ++nt) sfr[mt][nt] = vzero;
#pragma unroll
        for (int ks = 0; ks < 4; ++ks)
#pragma unroll
            for (int mt = 0; mt < 2; ++mt)
#pragma unroll
                for (int nt = 0; nt < 4; ++nt)
                    sfr[mt][nt] = __builtin_amdgcn_mfma_f32_16x16x32_bf16(kf[ks][nt], qf[mt][ks], sfr[mt][nt], 0, 0, 0);

        // V fragments direct from global (issued here; consumed after exp/transpose,
        // so their latency hides under the VALU phase): row = output d, col = k-pos
        bf16x8 vf[2][8];
#pragma unroll
        for (int ks2 = 0; ks2 < 2; ++ks2)
#pragma unroll
            for (int nt = 0; nt < 8; ++nt)
                vf[ks2][nt] = *(const bf16x8*)(vbb + (long)(nt * 16 + l16) * L_SEQ + ks2 * 32);

        // exp + pack to bf16 pair-words: pw[mt][nt][0]=(r0,r1), [1]=(r2,r3)
        unsigned int pw[2][4][2];
#pragma unroll
        for (int mt = 0; mt < 2; ++mt) {
#pragma unroll
            for (int nt = 0; nt < 4; ++nt) {
                float p0 = __expf(sfr[mt][nt][0] * scale);
                float p1 = __expf(sfr[mt][nt][1] * scale);
                float p2 = __expf(sfr[mt][nt][2] * scale);
                float p3 = __expf(sfr[mt][nt][3] * scale);
                lsum2[mt] += (p0 + p1) + (p2 + p3);
                pw[mt][nt][0] = pack_bf16x2(p0, p1);
                pw[mt][nt][1] = pack_bf16x2(p2, p3);
            }
        }

        // in-register transpose: build PV A-frags afr[mt][ks2] (k = ks2*32 + quad*8 + j)
        bf16x8 afr[2][2];
#pragma unroll
        for (int mt = 0; mt < 2; ++mt) {
#pragma unroll
            for (int ks2 = 0; ks2 < 2; ++ks2) {
                unsigned int P0 = pw[mt][ks2 * 2][0],     P1 = pw[mt][ks2 * 2][1];
                unsigned int Q0 = pw[mt][ks2 * 2 + 1][0], Q1 = pw[mt][ks2 * 2 + 1][1];
                asm("v_permlane32_swap_b32 %0, %1" : "+v"(P0), "+v"(Q0));
                asm("v_permlane32_swap_b32 %0, %1" : "+v"(P1), "+v"(Q1));
                unsigned int Px0 = __shfl_xor(P0, 16), Qx0 = __shfl_xor(Q0, 16);
                unsigned int Px1 = __shfl_xor(P1, 16), Qx1 = __shfl_xor(Q1, 16);
                union { unsigned int u[4]; bf16x8 v; } cv;
                cv.u[0] = qe ? P0  : Qx0;
                cv.u[1] = qe ? P1  : Qx1;
                cv.u[2] = qe ? Px0 : Q0;
                cv.u[3] = qe ? Px1 : Q1;
                afr[mt][ks2] = cv.v;
            }
        }

        // PV: O += P · V
#pragma unroll
        for (int ks2 = 0; ks2 < 2; ++ks2)
#pragma unroll
            for (int nt = 0; nt < 8; ++nt)
#pragma unroll
                for (int mt = 0; mt < 2; ++mt)
                    o_acc[mt][nt] = __builtin_amdgcn_mfma_f32_16x16x32_bf16(afr[mt][ks2], vf[ks2][nt], o_acc[mt][nt], 0, 0, 0);
    }

    const long pbase = (((long)(kc * NH + h) * NQB + qb)) * 128;
    // lsum: lane holds partial for q = mt*16 + l16 over its k-subset; reduce across quads
#pragma unroll
    for (int mt = 0; mt < 2; ++mt) {
        lsum2[mt] += __shfl_xor(lsum2[mt], 16);
        lsum2[mt] += __shfl_xor(lsum2[mt], 32);
        if (quad == 0) lsp[pbase + w * 32 + mt * 16 + l16] = lsum2[mt];
    }
#pragma unroll
    for (int mt = 0; mt < 2; ++mt) {
#pragma unroll
        for (int r = 0; r < 4; ++r) {
            const int row = w * 32 + mt * 16 + quad * 4 + r;
            float* od = Osp + (pbase + row) * 128;
#pragma unroll
            for (int nt = 0; nt < 8; ++nt)
                od[nt * 16 + l16] = o_acc[mt][nt][r];
        }
    }
}

extern "C" void kernel_launch(void* const* d_in, const int* in_sizes, int n_in,
                              void* d_out, int out_size, void* d_ws, size_t ws_size,
                              hipStream_t stream)
{
    const float* q = (const float*)d_in[0];
    const float* k = (const float*)d_in[1];
    const float* v = (const float*)d_in[2];
    const float* w = (const float*)d_in[3];
    const float* b = (const float*)d_in[4];
    float* out = (float*)d_out;
    char* ws = (char*)d_ws;

    __bf16* kb16 = (__bf16*)(ws + 0);          //  8,388,608  K bf16 [h][l][d]
    __bf16* vt16 = (__bf16*)(ws + 8388608);    //  8,388,608  V bf16 [h][d][l]
    float*  Osp  = (float*)(ws + 16777216);    // 33,554,432  sparse O partials [kc][h][qb][row][e]
    float*  kvp  = (float*)(ws + 16777216);    // 33,554,432  (alias) kv partials [h][ch][c][d]
    float*  lsp  = (float*)(ws + 50331648);    //    262,144  sparse l partials
    float*  pks  = (float*)(ws + 50593792);    //    262,144
    int*    lut  = (int*)  (ws + 50855936);    //     32,768
    float*  ksp  = (float*)(ws + 50888704);    //    262,144  ksum partials (64 chunks)
    float*  ksum = (float*)(ws + 51150848);    //      4,096
    __bf16* Mt   = (__bf16*)(ws + 51154944);   //    262,144  (kv @ W^T)^T bf16 [h][e][c]

    k_prep    <<<dim3(64, 8),   dim3(256), 0, stream>>>(k, v, kb16, vt16, pks, kvp, ksp);
    k_route   <<<dim3(32, 8),   dim3(256), 0, stream>>>(q, pks, lut);
    k_reduce_m<<<dim3(32, 8),   dim3(128), 0, stream>>>(kvp, ksp, w, Mt, ksum);
    k_sparse  <<<dim3(512),     dim3(256), 0, stream>>>(q, kb16, vt16, lut, Osp, lsp);
    k_linear  <<<dim3(32, 8),   dim3(256), 0, stream>>>(q, Mt, ksum, b, Osp, lsp, out); // writes d_out
}

// Round 5
// 229.063 us; speedup vs baseline: 1.2300x; 1.2300x over previous
//
#include <hip/hip_runtime.h>
#include <hip/hip_bf16.h>

#define L_SEQ 4096
#define NH 8
#define DH 128
#define NQB 32
#define NKB 64
#define TOPK 32
#define KVCH 64   // kv partial chunks per head (64 rows each) == blockIdx.x of fused prep

typedef __bf16 bf16x8 __attribute__((ext_vector_type(8)));
typedef __bf16 bf16x4 __attribute__((ext_vector_type(4)));
typedef float floatx4 __attribute__((ext_vector_type(4)));

static_assert(sizeof(bf16x8) == 16, "bf16x8 must be 16B");
static_assert(sizeof(bf16x4) == 8, "bf16x4 must be 8B");

// ---------------- fused prep v2: K->bf16 [h][l][d]; V->bf16 transposed [h][d][l]; pks;
// ---------------- feature-map softmax(K); kv outer-product partials via MFMA.
// fkT [c][l] bf16 and vTb [d][l] bf16 hold transposed operands so the 128x128x64 GEMM
// runs on matrix cores (32 MFMA/wave) instead of 8192 fp32 VALU FMAs/wave.
__global__ __launch_bounds__(256) void k_prep(const float* __restrict__ kin,
                                              const float* __restrict__ vin,
                                              __bf16* __restrict__ kb,
                                              __bf16* __restrict__ vt,
                                              float* __restrict__ pks,
                                              float* __restrict__ kvp,
                                              float* __restrict__ ksp)
{
    __shared__ __align__(16) float kt[64][132];      // raw K fp32 (pks) then softmaxed (ksp)
    __shared__ __align__(16) __bf16 fkT[128 * 72];   // softmax(K)^T  [c][l]
    __shared__ __align__(16) __bf16 vTb[128 * 72];   // V^T           [d][l]
    const int lb = blockIdx.x, h = blockIdx.y, t = threadIdx.x;
    const int r = t >> 2, seg = (t & 3) * 32;

    {   // stage K rows -> kt fp32 + kb16 global (coalesced)
        const float* ks = kin + ((long)((lb * 64 + r) * NH + h)) * DH + seg;
        float frK[32];
#pragma unroll
        for (int j = 0; j < 8; ++j) {
            float4 a = ((const float4*)ks)[j];
            float* kd = &kt[r][seg + 4 * j];
            kd[0] = a.x; kd[1] = a.y; kd[2] = a.z; kd[3] = a.w;
            frK[4 * j] = a.x; frK[4 * j + 1] = a.y; frK[4 * j + 2] = a.z; frK[4 * j + 3] = a.w;
        }
        bf16x8* kdst = (bf16x8*)(kb + ((long)(h * L_SEQ + lb * 64 + r)) * DH + seg);
#pragma unroll
        for (int g = 0; g < 4; ++g) {
            bf16x8 o;
#pragma unroll
            for (int e = 0; e < 8; ++e) o[e] = (__bf16)frK[g * 8 + e];
            kdst[g] = o;
        }
    }
    {   // stage V rows -> vTb bf16 transposed. vr = lane => d const per wave => conflict-free writes
        const int vr = t & 63, vs = (t >> 6) * 32;
        const float* vsrc = vin + ((long)((lb * 64 + vr) * NH + h)) * DH + vs;
#pragma unroll
        for (int j = 0; j < 8; ++j) {
            float4 b = ((const float4*)vsrc)[j];
            __bf16* vb = vTb + (vs + 4 * j) * 72 + vr;
            vb[0]   = (__bf16)b.x;
            vb[72]  = (__bf16)b.y;
            vb[144] = (__bf16)b.z;
            vb[216] = (__bf16)b.w;
        }
    }
    __syncthreads();

    if (t < 128) {   // pks: RAW K column sums (kt not yet overwritten)
        float s = 0.f;
#pragma unroll 8
        for (int rr = 0; rr < 64; ++rr) s += kt[rr][t];
        pks[((long)(h * NKB + lb)) * DH + t] = s;
    }
    {   // vt16 global write: contiguous b128 reads of vTb rows
        const int d = t >> 1, lh2 = (t & 1) * 32;
        const bf16x8* src = (const bf16x8*)(vTb + d * 72 + lh2);
        bf16x8* dst = (bf16x8*)(vt + ((long)(h * DH + d)) * L_SEQ + lb * 64 + lh2);
#pragma unroll
        for (int j = 0; j < 4; ++j) dst[j] = src[j];
    }
    float vals[32];
    {   // feature-map softmax over D (read kt rows; result in regs) -> fkT bf16 scatter
        const float* fr = &kt[r][seg];
#pragma unroll
        for (int j = 0; j < 8; ++j) {
            float4 x = ((const float4*)fr)[j];
            vals[4*j] = x.x; vals[4*j+1] = x.y; vals[4*j+2] = x.z; vals[4*j+3] = x.w;
        }
        float mx = -__builtin_inff();
#pragma unroll
        for (int c = 0; c < 32; ++c) mx = fmaxf(mx, vals[c]);
        mx = fmaxf(mx, __shfl_xor(mx, 1));
        mx = fmaxf(mx, __shfl_xor(mx, 2));
        float sm = 0.f;
#pragma unroll
        for (int c = 0; c < 32; ++c) { vals[c] = __expf(vals[c] - mx); sm += vals[c]; }
        sm += __shfl_xor(sm, 1);
        sm += __shfl_xor(sm, 2);
        const float inv = 1.f / sm;
#pragma unroll
        for (int c = 0; c < 32; ++c) vals[c] *= inv;
        __bf16* fb = fkT + seg * 72 + r;
#pragma unroll
        for (int j = 0; j < 32; ++j) fb[j * 72] = (__bf16)vals[j];
    }
    __syncthreads();   // pks col-reads done; fkT/vTb complete

    {   // kt writeback (softmaxed, fp32) for the fp32 ksp column sums
        float* fr = &kt[r][seg];
#pragma unroll
        for (int j = 0; j < 8; ++j) {
            float4 x = {vals[4*j], vals[4*j+1], vals[4*j+2], vals[4*j+3]};
            ((float4*)fr)[j] = x;
        }
    }
    {   // kv partials via MFMA: kv[c][d] = sum_l fk[l][c] * V[l][d]
        const int w = t >> 6, lane = t & 63, l16 = lane & 15, quad = lane >> 4;
        const floatx4 vzero = {0.f, 0.f, 0.f, 0.f};
        floatx4 acc[2][8];
#pragma unroll
        for (int mt = 0; mt < 2; ++mt)
#pragma unroll
            for (int nt = 0; nt < 8; ++nt) acc[mt][nt] = vzero;
#pragma unroll
        for (int ks = 0; ks < 2; ++ks) {
            bf16x8 afr[2];
#pragma unroll
            for (int mt = 0; mt < 2; ++mt)
                afr[mt] = *(const bf16x8*)(fkT + (w * 32 + mt * 16 + l16) * 72 + ks * 32 + quad * 8);
#pragma unroll
            for (int nt = 0; nt < 8; ++nt) {
                bf16x8 bfr = *(const bf16x8*)(vTb + (nt * 16 + l16) * 72 + ks * 32 + quad * 8);
#pragma unroll
                for (int mt = 0; mt < 2; ++mt)
                    acc[mt][nt] = __builtin_amdgcn_mfma_f32_16x16x32_bf16(afr[mt], bfr, acc[mt][nt], 0, 0, 0);
            }
        }
        // acc[mt][nt][r4] = kv[c = w*32 + mt*16 + quad*4 + r4][d = nt*16 + l16]
#pragma unroll
        for (int mt = 0; mt < 2; ++mt) {
#pragma unroll
            for (int r4 = 0; r4 < 4; ++r4) {
                const int c = w * 32 + mt * 16 + quad * 4 + r4;
                float* dst = kvp + (((long)(h * KVCH + lb) * 128) + c) * 128;
#pragma unroll
                for (int nt = 0; nt < 8; ++nt)
                    dst[nt * 16 + l16] = acc[mt][nt][r4];
            }
        }
    }
    __syncthreads();   // kt writeback complete
    if (t < 128) {   // ksp: fp32 column sums of softmaxed kt (denominator path stays fp32)
        float s = 0.f;
#pragma unroll 8
        for (int rr = 0; rr < 64; ++rr) s += kt[rr][t];
        ksp[(h * KVCH + lb) * 128 + t] = s;
    }
}

// ---------------- routing (fused Q-pool): rank-based top-32 ----------------
__global__ __launch_bounds__(256) void k_route(const float* __restrict__ q,
                                               const float* __restrict__ pks,
                                               int* __restrict__ lut)
{
    __shared__ float qv[128];
    __shared__ float qv2[128];
    __shared__ float sc[64];
    const int qi = blockIdx.x, h = blockIdx.y, t = threadIdx.x;
    {
        const int d = t & 127, half = t >> 7;
        float acc = 0.f;
        const int r0 = half * 64;
#pragma unroll 4
        for (int r = 0; r < 64; ++r)
            acc += q[((long)((qi * 128 + r0 + r) * NH + h)) * DH + d];
        if (half == 0) qv[d] = acc; else qv2[d] = acc;
    }
    __syncthreads();
    if (t < 128) qv[t] += qv2[t];
    __syncthreads();
    if (t < 64) {
        const float4* pr = (const float4*)(pks + ((long)(h * NKB + t)) * DH);
        const float4* qp = (const float4*)qv;
        float s = 0.f;
#pragma unroll 8
        for (int d4 = 0; d4 < 32; ++d4) {
            float4 a = qp[d4], b = pr[d4];
            s += a.x * b.x + a.y * b.y + a.z * b.z + a.w * b.w;
        }
        sc[t] = s;
    }
    __syncthreads();
    if (t < 64) {
        const float s = sc[t];
        int rank = 0;
        for (int j2 = 0; j2 < 64; ++j2) {
            float o = sc[j2];
            rank += (o > s) || (o == s && j2 < t);
        }
        if (rank < TOPK) lut[(h * NQB + qi) * TOPK + rank] = t;
    }
}

// ---------------- reduce partials; Mt[h][e][c] = (kv @ W^T)^T in bf16; ksum ----------------
__global__ __launch_bounds__(128) void k_reduce_m(const float* __restrict__ kvp,
                                                  const float* __restrict__ ksp,
                                                  const float* __restrict__ w,
                                                  __bf16* __restrict__ Mt,
                                                  float* __restrict__ ksum)
{
    __shared__ float wt[128][129];   // [d][e]
    __shared__ float kvr[4][128];
    __shared__ float shks[4][64];
    const int cb = blockIdx.x, h = blockIdx.y, t = threadIdx.x;
    const int c0 = cb * 4;
    {   // W transpose: coalesced loads, 2-way-free LDS writes
#pragma unroll 8
        for (int e = 0; e < 128; ++e) wt[t][e] = w[(long)e * DH + t];
    }
    {   // reduce kv partials for 4 c-rows
#pragma unroll
        for (int r = 0; r < 4; ++r) {
            float acc = 0.f;
            for (int ch = 0; ch < KVCH; ++ch)
                acc += kvp[(((long)(h * KVCH + ch) * 128) + c0 + r) * 128 + t];
            kvr[r][t] = acc;
        }
    }
    for (int i = t; i < 256; i += 128) {   // ksum partial stage
        const int r = i >> 6, ch = i & 63;
        shks[r][ch] = ksp[(h * KVCH + ch) * 128 + c0 + r];
    }
    __syncthreads();
    if (t < 4) {
        float s = 0.f;
#pragma unroll
        for (int ch = 0; ch < 64; ++ch) s += shks[t][ch];
        ksum[h * 128 + c0 + t] = s;
    }
    float m[4] = {0.f, 0.f, 0.f, 0.f};
#pragma unroll 4
    for (int d = 0; d < 128; ++d) {
        const float wv = wt[d][t];
#pragma unroll
        for (int r = 0; r < 4; ++r) m[r] += kvr[r][d] * wv;
    }
    // lane t owns Mt[e=t][c0..c0+3] -> one 8B store
    bf16x4 pk;
#pragma unroll
    for (int r = 0; r < 4; ++r) pk[r] = (__bf16)m[r];
    *(bf16x4*)(Mt + ((long)(h * 128 + t)) * 128 + c0) = pk;
}

// ---------------- linear apply (MFMA) + sparse merge: writes d_out, runs LAST ----------------
__global__ __launch_bounds__(256) void k_linear(const float* __restrict__ q,
                                                const __bf16* __restrict__ Mt,
                                                const float* __restrict__ ksum,
                                                const float* __restrict__ bproj,
                                                const float* __restrict__ Osp,
                                                const float* __restrict__ lsp,
                                                float* __restrict__ out)
{
    __shared__ __align__(16) __bf16 fq[128 * 136];   // raw exp, stride 136
    __shared__ float dinv[128];
    __shared__ float dsp[128];
    const int qb = blockIdx.x, h = blockIdx.y, t = threadIdx.x;
    const int l0 = qb * 128;

    {   // phase 1: per-row raw-exp + fused denominator; 2 threads/row
        const int row = t >> 1, half = t & 1;
        const float* qrow = q + ((long)((l0 + row) * NH + h)) * DH + half * 64;
        float vals[64];
#pragma unroll
        for (int j = 0; j < 16; ++j) {
            float4 x = ((const float4*)qrow)[j];
            vals[4*j] = x.x; vals[4*j+1] = x.y; vals[4*j+2] = x.z; vals[4*j+3] = x.w;
        }
        float mx = -__builtin_inff();
#pragma unroll
        for (int c = 0; c < 64; ++c) mx = fmaxf(mx, vals[c]);
        mx = fmaxf(mx, __shfl_xor(mx, 1));
        float sm = 0.f, dk = 0.f;
        const float* ks = ksum + h * DH + half * 64;
#pragma unroll
        for (int c = 0; c < 64; ++c) {
            float e = __expf(vals[c] - mx);
            vals[c] = e; sm += e; dk += e * ks[c];
        }
        __bf16* dst = fq + row * 136 + half * 64;
#pragma unroll
        for (int g = 0; g < 8; ++g) {
            bf16x8 o;
#pragma unroll
            for (int e2 = 0; e2 < 8; ++e2) o[e2] = (__bf16)vals[g * 8 + e2];
            *(bf16x8*)(dst + g * 8) = o;
        }
        sm += __shfl_xor(sm, 1);
        dk += __shfl_xor(dk, 1);
        if (half == 0) dinv[row] = 1.f / (1e-5f * sm + dk);
    }
    if (t < 128) {
        const long p0 = ((long)(h * NQB + qb)) * 128 + t;
        const long p1 = ((long)((NH + h) * NQB + qb)) * 128 + t;
        dsp[t] = 1.f / (lsp[p0] + lsp[p1]);
    }
    __syncthreads();

    // phase 2: MFMA  [128 rows x 128 e], wave w owns rows w*32..+32
    const int w = t >> 6, lane = t & 63, l16 = lane & 15, quad = lane >> 4;
    const __bf16* Bh = Mt + (long)h * DH * DH;
    const floatx4 vzero = {0.f, 0.f, 0.f, 0.f};
    floatx4 acc[2][8];
#pragma unroll
    for (int mt = 0; mt < 2; ++mt)
#pragma unroll
        for (int nt = 0; nt < 8; ++nt) acc[mt][nt] = vzero;
#pragma unroll
    for (int ksx = 0; ksx < 4; ++ksx) {
        bf16x8 af[2];
#pragma unroll
        for (int mt = 0; mt < 2; ++mt)
            af[mt] = *(const bf16x8*)(fq + (w * 32 + mt * 16 + l16) * 136 + ksx * 32 + quad * 8);
#pragma unroll
        for (int nt = 0; nt < 8; ++nt) {
            bf16x8 bf = *(const bf16x8*)(Bh + ((long)(nt * 16 + l16)) * DH + ksx * 32 + quad * 8);
#pragma unroll
            for (int mt = 0; mt < 2; ++mt)
                acc[mt][nt] = __builtin_amdgcn_mfma_f32_16x16x32_bf16(af[mt], bf, acc[mt][nt], 0, 0, 0);
        }
    }

    // epilogue: denom, bias, sparse merge
    float bias[8];
#pragma unroll
    for (int nt = 0; nt < 8; ++nt) bias[nt] = bproj[nt * 16 + l16];
    const float* O0b = Osp + (((long)(h * NQB + qb)) * 128) * 128;
    const float* O1b = Osp + (((long)((NH + h) * NQB + qb)) * 128) * 128;
#pragma unroll
    for (int mt = 0; mt < 2; ++mt) {
#pragma unroll
        for (int r = 0; r < 4; ++r) {
            const int row = w * 32 + mt * 16 + quad * 4 + r;
            const float di = dinv[row], ds = dsp[row];
            float* op = out + ((long)((l0 + row) * NH + h)) * DH;
            const float* o0 = O0b + (long)row * 128;
            const float* o1 = O1b + (long)row * 128;
#pragma unroll
            for (int nt = 0; nt < 8; ++nt) {
                const int e = nt * 16 + l16;
                op[e] = acc[mt][nt][r] * di + bias[nt] + (o0[e] + o1[e]) * ds;
            }
        }
    }
}

// ---------------- sparse flash attention (r3 structure, verified): swapped QK^T,
// ---------------- register-P transpose, double-buffered K/V LDS, one barrier/iter.
// ---------------- + V-frag hoist before exp (DS latency under VALU) + T5 setprio.
#define SM_K0   0
#define SM_K1   17408
#define SM_V0   34816
#define SM_V1   53248
#define SM_LUT  71680
#define SM_SZ   71744

static __device__ __forceinline__ unsigned int pack_bf16x2(float lo, float hi)
{
    union { __bf16 h[2]; unsigned int u; } cv;
    cv.h[0] = (__bf16)lo; cv.h[1] = (__bf16)hi;
    return cv.u;
}

__global__ __launch_bounds__(256, 2) void k_sparse(const float* __restrict__ q,
                                                   const __bf16* __restrict__ kb16,
                                                   const __bf16* __restrict__ vt16,
                                                   const int* __restrict__ lut,
                                                   float* __restrict__ Osp,
                                                   float* __restrict__ lsp)
{
    __shared__ __align__(16) char smem[SM_SZ];
    int* luts = (int*)(smem + SM_LUT);

    const int id = blockIdx.x;
    const int xcd = id & 7, slot = id >> 3;
    const int pair = xcd + 8 * (slot >> 5);   // 0..15
    const int qb = slot & 31;
    const int h = pair >> 1, kc = pair & 1;
    const int t = threadIdx.x;
    const int w = t >> 6;
    const int lane = t & 63;
    const int l16 = lane & 15;
    const int quad = lane >> 4;
    const bool qe = (quad & 1) == 0;          // quad even?

    if (t < 16) luts[t] = lut[(h * NQB + qb) * TOPK + kc * 16 + t];

    bf16x8 qf[2][4];
#pragma unroll
    for (int mt = 0; mt < 2; ++mt) {
        const int gl = qb * 128 + w * 32 + mt * 16 + l16;
        const float* qrow = q + ((long)(gl * NH + h)) * DH;
#pragma unroll
        for (int ks = 0; ks < 4; ++ks) {
            const float4* s2 = (const float4*)(qrow + ks * 32 + quad * 8);
            float4 a = s2[0], b = s2[1];
            bf16x8 f;
            f[0] = (__bf16)a.x; f[1] = (__bf16)a.y; f[2] = (__bf16)a.z; f[3] = (__bf16)a.w;
            f[4] = (__bf16)b.x; f[5] = (__bf16)b.y; f[6] = (__bf16)b.z; f[7] = (__bf16)b.w;
            qf[mt][ks] = f;
        }
    }

    const floatx4 vzero = {0.f, 0.f, 0.f, 0.f};
    floatx4 o_acc[2][8];
#pragma unroll
    for (int mt = 0; mt < 2; ++mt)
#pragma unroll
        for (int nt = 0; nt < 8; ++nt) o_acc[mt][nt] = vzero;
    float lsum2[2] = {0.f, 0.f};

    const float scale = 0.08838834764831845f;
    const __bf16* kbh = kb16 + (long)h * L_SEQ * DH;
    const __bf16* vth = vt16 + (long)h * DH * L_SEQ;
    int kr[4], kc8[4], vr[4], vc8[4];
#pragma unroll
    for (int j = 0; j < 4; ++j) {
        const int si = t + j * 256;
        kr[j] = si >> 4; kc8[j] = si & 15;
        vr[j] = si >> 3; vc8[j] = si & 7;
    }

    __syncthreads();   // luts ready

    // prologue: tile0 -> buf0; prefetch tile1 -> regs
    {
        const int b0 = luts[0];
        __bf16* K0 = (__bf16*)(smem + SM_K0);
        __bf16* V0 = (__bf16*)(smem + SM_V0);
#pragma unroll
        for (int j = 0; j < 4; ++j) {
            bf16x8 kk = *(const bf16x8*)(kbh + ((long)(b0 * 64 + kr[j])) * DH + kc8[j] * 8);
            bf16x8 vv = *(const bf16x8*)(vth + (long)vr[j] * L_SEQ + b0 * 64 + vc8[j] * 8);
            *(bf16x8*)(K0 + kr[j] * 136 + kc8[j] * 8) = kk;
            *(bf16x8*)(V0 + vr[j] * 72 + vc8[j] * 8)  = vv;
        }
    }
    bf16x8 pk[4], pv[4];
    {
        const int b1 = luts[1];
#pragma unroll
        for (int j = 0; j < 4; ++j) {
            pk[j] = *(const bf16x8*)(kbh + ((long)(b1 * 64 + kr[j])) * DH + kc8[j] * 8);
            pv[j] = *(const bf16x8*)(vth + (long)vr[j] * L_SEQ + b1 * 64 + vc8[j] * 8);
        }
    }
    __syncthreads();   // buf0 ready

    for (int it = 0; it < 16; ++it) {
        const int cur = it & 1;
        const __bf16* Kc = (const __bf16*)(smem + (cur ? SM_K1 : SM_K0));
        const __bf16* Vc = (const __bf16*)(smem + (cur ? SM_V1 : SM_V0));

        if (it < 15) {   // write tile it+1 (regs) -> other buffer
            __bf16* Kn = (__bf16*)(smem + (cur ? SM_K0 : SM_K1));
            __bf16* Vn = (__bf16*)(smem + (cur ? SM_V0 : SM_V1));
#pragma unroll
            for (int j = 0; j < 4; ++j) {
                *(bf16x8*)(Kn + kr[j] * 136 + kc8[j] * 8) = pk[j];
                *(bf16x8*)(Vn + vr[j] * 72 + vc8[j] * 8)  = pv[j];
            }
        }
        if (it < 14) {   // prefetch tile it+2 -> regs
            const int b2 = luts[it + 2];
#pragma unroll
            for (int j = 0; j < 4; ++j) {
                pk[j] = *(const bf16x8*)(kbh + ((long)(b2 * 64 + kr[j])) * DH + kc8[j] * 8);
                pv[j] = *(const bf16x8*)(vth + (long)vr[j] * L_SEQ + b2 * 64 + vc8[j] * 8);
            }
        }

        // swapped QK^T: sfr[mt][nt][r] = S[q = mt*16 + l16][k = nt*16 + quad*4 + r]
        floatx4 sfr[2][4];
#pragma unroll
        for (int mt = 0; mt < 2; ++mt)
#pragma unroll
            for (int nt = 0; nt < 4; ++nt) sfr[mt][nt] = vzero;
        __builtin_amdgcn_s_setprio(1);
#pragma unroll
        for (int ks = 0; ks < 4; ++ks) {
            bf16x8 bf[4];
#pragma unroll
            for (int nt = 0; nt < 4; ++nt)
                bf[nt] = *(const bf16x8*)(Kc + (nt * 16 + l16) * 136 + ks * 32 + quad * 8);
#pragma unroll
            for (int mt = 0; mt < 2; ++mt)
#pragma unroll
                for (int nt = 0; nt < 4; ++nt)
                    sfr[mt][nt] = __builtin_amdgcn_mfma_f32_16x16x32_bf16(bf[nt], qf[mt][ks], sfr[mt][nt], 0, 0, 0);
        }
        __builtin_amdgcn_s_setprio(0);

        // hoist V-frag LDS reads: latency hides under the exp/transpose VALU phase
        bf16x8 vf[2][8];
#pragma unroll
        for (int ks2 = 0; ks2 < 2; ++ks2)
#pragma unroll
            for (int nt = 0; nt < 8; ++nt)
                vf[ks2][nt] = *(const bf16x8*)(Vc + (nt * 16 + l16) * 72 + ks2 * 32 + quad * 8);

        // exp + pack to bf16 pair-words: pw[mt][nt][0]=(r0,r1), [1]=(r2,r3)
        unsigned int pw[2][4][2];
#pragma unroll
        for (int mt = 0; mt < 2; ++mt) {
#pragma unroll
            for (int nt = 0; nt < 4; ++nt) {
                float p0 = __expf(sfr[mt][nt][0] * scale);
                float p1 = __expf(sfr[mt][nt][1] * scale);
                float p2 = __expf(sfr[mt][nt][2] * scale);
                float p3 = __expf(sfr[mt][nt][3] * scale);
                lsum2[mt] += (p0 + p1) + (p2 + p3);
                pw[mt][nt][0] = pack_bf16x2(p0, p1);
                pw[mt][nt][1] = pack_bf16x2(p2, p3);
            }
        }

        // in-register transpose: build PV A-frags afr[mt][ks2] (k = ks2*32 + quad*8 + j)
        bf16x8 afr[2][2];
#pragma unroll
        for (int mt = 0; mt < 2; ++mt) {
#pragma unroll
            for (int ks2 = 0; ks2 < 2; ++ks2) {
                unsigned int P0 = pw[mt][ks2 * 2][0],     P1 = pw[mt][ks2 * 2][1];
                unsigned int Q0 = pw[mt][ks2 * 2 + 1][0], Q1 = pw[mt][ks2 * 2 + 1][1];
                asm("v_permlane32_swap_b32 %0, %1" : "+v"(P0), "+v"(Q0));
                asm("v_permlane32_swap_b32 %0, %1" : "+v"(P1), "+v"(Q1));
                unsigned int Px0 = __shfl_xor(P0, 16), Qx0 = __shfl_xor(Q0, 16);
                unsigned int Px1 = __shfl_xor(P1, 16), Qx1 = __shfl_xor(Q1, 16);
                union { unsigned int u[4]; bf16x8 v; } cv;
                cv.u[0] = qe ? P0  : Qx0;
                cv.u[1] = qe ? P1  : Qx1;
                cv.u[2] = qe ? Px0 : Q0;
                cv.u[3] = qe ? Px1 : Q1;
                afr[mt][ks2] = cv.v;
            }
        }

        // PV: O += P · V
        __builtin_amdgcn_s_setprio(1);
#pragma unroll
        for (int ks2 = 0; ks2 < 2; ++ks2)
#pragma unroll
            for (int nt = 0; nt < 8; ++nt)
#pragma unroll
                for (int mt = 0; mt < 2; ++mt)
                    o_acc[mt][nt] = __builtin_amdgcn_mfma_f32_16x16x32_bf16(afr[mt][ks2], vf[ks2][nt], o_acc[mt][nt], 0, 0, 0);
        __builtin_amdgcn_s_setprio(0);
        __syncthreads();   // single barrier per iteration
    }

    const long pbase = (((long)(kc * NH + h) * NQB + qb)) * 128;
#pragma unroll
    for (int mt = 0; mt < 2; ++mt) {
        lsum2[mt] += __shfl_xor(lsum2[mt], 16);
        lsum2[mt] += __shfl_xor(lsum2[mt], 32);
        if (quad == 0) lsp[pbase + w * 32 + mt * 16 + l16] = lsum2[mt];
    }
#pragma unroll
    for (int mt = 0; mt < 2; ++mt) {
#pragma unroll
        for (int r = 0; r < 4; ++r) {
            const int row = w * 32 + mt * 16 + quad * 4 + r;
            float* od = Osp + (pbase + row) * 128;
#pragma unroll
            for (int nt = 0; nt < 8; ++nt)
                od[nt * 16 + l16] = o_acc[mt][nt][r];
        }
    }
}

extern "C" void kernel_launch(void* const* d_in, const int* in_sizes, int n_in,
                              void* d_out, int out_size, void* d_ws, size_t ws_size,
                              hipStream_t stream)
{
    const float* q = (const float*)d_in[0];
    const float* k = (const float*)d_in[1];
    const float* v = (const float*)d_in[2];
    const float* w = (const float*)d_in[3];
    const float* b = (const float*)d_in[4];
    float* out = (float*)d_out;
    char* ws = (char*)d_ws;

    __bf16* kb16 = (__bf16*)(ws + 0);          //  8,388,608  K bf16 [h][l][d]
    __bf16* vt16 = (__bf16*)(ws + 8388608);    //  8,388,608  V bf16 [h][d][l]
    float*  Osp  = (float*)(ws + 16777216);    // 33,554,432  sparse O partials [kc][h][qb][row][e]
    float*  kvp  = (float*)(ws + 16777216);    // 33,554,432  (alias) kv partials [h][ch][c][d]
    float*  lsp  = (float*)(ws + 50331648);    //    262,144  sparse l partials
    float*  pks  = (float*)(ws + 50593792);    //    262,144
    int*    lut  = (int*)  (ws + 50855936);    //     32,768
    float*  ksp  = (float*)(ws + 50888704);    //    262,144  ksum partials (64 chunks)
    float*  ksum = (float*)(ws + 51150848);    //      4,096
    __bf16* Mt   = (__bf16*)(ws + 51154944);   //    262,144  (kv @ W^T)^T bf16 [h][e][c]

    k_prep    <<<dim3(64, 8),   dim3(256), 0, stream>>>(k, v, kb16, vt16, pks, kvp, ksp);
    k_route   <<<dim3(32, 8),   dim3(256), 0, stream>>>(q, pks, lut);
    k_reduce_m<<<dim3(32, 8),   dim3(128), 0, stream>>>(kvp, ksp, w, Mt, ksum);
    k_sparse  <<<dim3(512),     dim3(256), 0, stream>>>(q, kb16, vt16, lut, Osp, lsp);
    k_linear  <<<dim3(32, 8),   dim3(256), 0, stream>>>(q, Mt, ksum, b, Osp, lsp, out); // writes d_out
}

// Round 7
// 203.231 us; speedup vs baseline: 1.3864x; 1.1271x over previous
//
#include <hip/hip_runtime.h>
#include <hip/hip_bf16.h>

#define L_SEQ 4096
#define NH 8
#define DH 128
#define NQB 32
#define NKB 64
#define TOPK 32
#define KVCH 64   // kv partial chunks per head (64 rows each) == blockIdx.x of fused prep

typedef __bf16 bf16x8 __attribute__((ext_vector_type(8)));
typedef __bf16 bf16x4 __attribute__((ext_vector_type(4)));
typedef float floatx4 __attribute__((ext_vector_type(4)));

static_assert(sizeof(bf16x8) == 16, "bf16x8 must be 16B");
static_assert(sizeof(bf16x4) == 8, "bf16x4 must be 8B");

// ---------------- fused prep v2: K->bf16 [h][l][d]; V->bf16 transposed [h][d][l]; pks;
// ---------------- feature-map softmax(K); kv outer-product partials via MFMA. (r5-verified, ~8 us win)
__global__ __launch_bounds__(256) void k_prep(const float* __restrict__ kin,
                                              const float* __restrict__ vin,
                                              __bf16* __restrict__ kb,
                                              __bf16* __restrict__ vt,
                                              float* __restrict__ pks,
                                              float* __restrict__ kvp,
                                              float* __restrict__ ksp)
{
    __shared__ __align__(16) float kt[64][132];      // raw K fp32 (pks) then softmaxed (ksp)
    __shared__ __align__(16) __bf16 fkT[128 * 72];   // softmax(K)^T  [c][l]
    __shared__ __align__(16) __bf16 vTb[128 * 72];   // V^T           [d][l]
    const int lb = blockIdx.x, h = blockIdx.y, t = threadIdx.x;
    const int r = t >> 2, seg = (t & 3) * 32;

    {   // stage K rows -> kt fp32 + kb16 global (coalesced)
        const float* ks = kin + ((long)((lb * 64 + r) * NH + h)) * DH + seg;
        float frK[32];
#pragma unroll
        for (int j = 0; j < 8; ++j) {
            float4 a = ((const float4*)ks)[j];
            float* kd = &kt[r][seg + 4 * j];
            kd[0] = a.x; kd[1] = a.y; kd[2] = a.z; kd[3] = a.w;
            frK[4 * j] = a.x; frK[4 * j + 1] = a.y; frK[4 * j + 2] = a.z; frK[4 * j + 3] = a.w;
        }
        bf16x8* kdst = (bf16x8*)(kb + ((long)(h * L_SEQ + lb * 64 + r)) * DH + seg);
#pragma unroll
        for (int g = 0; g < 4; ++g) {
            bf16x8 o;
#pragma unroll
            for (int e = 0; e < 8; ++e) o[e] = (__bf16)frK[g * 8 + e];
            kdst[g] = o;
        }
    }
    {   // stage V rows -> vTb bf16 transposed. vr = lane => d const per wave => conflict-free writes
        const int vr = t & 63, vs = (t >> 6) * 32;
        const float* vsrc = vin + ((long)((lb * 64 + vr) * NH + h)) * DH + vs;
#pragma unroll
        for (int j = 0; j < 8; ++j) {
            float4 b = ((const float4*)vsrc)[j];
            __bf16* vb = vTb + (vs + 4 * j) * 72 + vr;
            vb[0]   = (__bf16)b.x;
            vb[72]  = (__bf16)b.y;
            vb[144] = (__bf16)b.z;
            vb[216] = (__bf16)b.w;
        }
    }
    __syncthreads();

    if (t < 128) {   // pks: RAW K column sums (kt not yet overwritten)
        float s = 0.f;
#pragma unroll 8
        for (int rr = 0; rr < 64; ++rr) s += kt[rr][t];
        pks[((long)(h * NKB + lb)) * DH + t] = s;
    }
    {   // vt16 global write: contiguous b128 reads of vTb rows
        const int d = t >> 1, lh2 = (t & 1) * 32;
        const bf16x8* src = (const bf16x8*)(vTb + d * 72 + lh2);
        bf16x8* dst = (bf16x8*)(vt + ((long)(h * DH + d)) * L_SEQ + lb * 64 + lh2);
#pragma unroll
        for (int j = 0; j < 4; ++j) dst[j] = src[j];
    }
    float vals[32];
    {   // feature-map softmax over D (read kt rows; result in regs) -> fkT bf16 scatter
        const float* fr = &kt[r][seg];
#pragma unroll
        for (int j = 0; j < 8; ++j) {
            float4 x = ((const float4*)fr)[j];
            vals[4*j] = x.x; vals[4*j+1] = x.y; vals[4*j+2] = x.z; vals[4*j+3] = x.w;
        }
        float mx = -__builtin_inff();
#pragma unroll
        for (int c = 0; c < 32; ++c) mx = fmaxf(mx, vals[c]);
        mx = fmaxf(mx, __shfl_xor(mx, 1));
        mx = fmaxf(mx, __shfl_xor(mx, 2));
        float sm = 0.f;
#pragma unroll
        for (int c = 0; c < 32; ++c) { vals[c] = __expf(vals[c] - mx); sm += vals[c]; }
        sm += __shfl_xor(sm, 1);
        sm += __shfl_xor(sm, 2);
        const float inv = 1.f / sm;
#pragma unroll
        for (int c = 0; c < 32; ++c) vals[c] *= inv;
        __bf16* fb = fkT + seg * 72 + r;
#pragma unroll
        for (int j = 0; j < 32; ++j) fb[j * 72] = (__bf16)vals[j];
    }
    __syncthreads();   // pks col-reads done; fkT/vTb complete

    {   // kt writeback (softmaxed, fp32) for the fp32 ksp column sums
        float* fr = &kt[r][seg];
#pragma unroll
        for (int j = 0; j < 8; ++j) {
            float4 x = {vals[4*j], vals[4*j+1], vals[4*j+2], vals[4*j+3]};
            ((float4*)fr)[j] = x;
        }
    }
    {   // kv partials via MFMA: kv[c][d] = sum_l fk[l][c] * V[l][d]
        const int w = t >> 6, lane = t & 63, l16 = lane & 15, quad = lane >> 4;
        const floatx4 vzero = {0.f, 0.f, 0.f, 0.f};
        floatx4 acc[2][8];
#pragma unroll
        for (int mt = 0; mt < 2; ++mt)
#pragma unroll
            for (int nt = 0; nt < 8; ++nt) acc[mt][nt] = vzero;
#pragma unroll
        for (int ks = 0; ks < 2; ++ks) {
            bf16x8 afr[2];
#pragma unroll
            for (int mt = 0; mt < 2; ++mt)
                afr[mt] = *(const bf16x8*)(fkT + (w * 32 + mt * 16 + l16) * 72 + ks * 32 + quad * 8);
#pragma unroll
            for (int nt = 0; nt < 8; ++nt) {
                bf16x8 bfr = *(const bf16x8*)(vTb + (nt * 16 + l16) * 72 + ks * 32 + quad * 8);
#pragma unroll
                for (int mt = 0; mt < 2; ++mt)
                    acc[mt][nt] = __builtin_amdgcn_mfma_f32_16x16x32_bf16(afr[mt], bfr, acc[mt][nt], 0, 0, 0);
            }
        }
        // acc[mt][nt][r4] = kv[c = w*32 + mt*16 + quad*4 + r4][d = nt*16 + l16]
#pragma unroll
        for (int mt = 0; mt < 2; ++mt) {
#pragma unroll
            for (int r4 = 0; r4 < 4; ++r4) {
                const int c = w * 32 + mt * 16 + quad * 4 + r4;
                float* dst = kvp + (((long)(h * KVCH + lb) * 128) + c) * 128;
#pragma unroll
                for (int nt = 0; nt < 8; ++nt)
                    dst[nt * 16 + l16] = acc[mt][nt][r4];
            }
        }
    }
    __syncthreads();   // kt writeback complete
    if (t < 128) {   // ksp: fp32 column sums of softmaxed kt (denominator path stays fp32)
        float s = 0.f;
#pragma unroll 8
        for (int rr = 0; rr < 64; ++rr) s += kt[rr][t];
        ksp[(h * KVCH + lb) * 128 + t] = s;
    }
}

// ---------------- routing (fused Q-pool): rank-based top-32 ----------------
__global__ __launch_bounds__(256) void k_route(const float* __restrict__ q,
                                               const float* __restrict__ pks,
                                               int* __restrict__ lut)
{
    __shared__ float qv[128];
    __shared__ float qv2[128];
    __shared__ float sc[64];
    const int qi = blockIdx.x, h = blockIdx.y, t = threadIdx.x;
    {
        const int d = t & 127, half = t >> 7;
        float acc = 0.f;
        const int r0 = half * 64;
#pragma unroll 4
        for (int r = 0; r < 64; ++r)
            acc += q[((long)((qi * 128 + r0 + r) * NH + h)) * DH + d];
        if (half == 0) qv[d] = acc; else qv2[d] = acc;
    }
    __syncthreads();
    if (t < 128) qv[t] += qv2[t];
    __syncthreads();
    if (t < 64) {
        const float4* pr = (const float4*)(pks + ((long)(h * NKB + t)) * DH);
        const float4* qp = (const float4*)qv;
        float s = 0.f;
#pragma unroll 8
        for (int d4 = 0; d4 < 32; ++d4) {
            float4 a = qp[d4], b = pr[d4];
            s += a.x * b.x + a.y * b.y + a.z * b.z + a.w * b.w;
        }
        sc[t] = s;
    }
    __syncthreads();
    if (t < 64) {
        const float s = sc[t];
        int rank = 0;
        for (int j2 = 0; j2 < 64; ++j2) {
            float o = sc[j2];
            rank += (o > s) || (o == s && j2 < t);
        }
        if (rank < TOPK) lut[(h * NQB + qi) * TOPK + rank] = t;
    }
}

// ---------------- reduce partials; Mt[h][e][c] = (kv @ W^T)^T in bf16; ksum ----------------
__global__ __launch_bounds__(128) void k_reduce_m(const float* __restrict__ kvp,
                                                  const float* __restrict__ ksp,
                                                  const float* __restrict__ w,
                                                  __bf16* __restrict__ Mt,
                                                  float* __restrict__ ksum)
{
    __shared__ float wt[128][129];   // [d][e]
    __shared__ float kvr[4][128];
    __shared__ float shks[4][64];
    const int cb = blockIdx.x, h = blockIdx.y, t = threadIdx.x;
    const int c0 = cb * 4;
    {   // W transpose: coalesced loads, 2-way-free LDS writes
#pragma unroll 8
        for (int e = 0; e < 128; ++e) wt[t][e] = w[(long)e * DH + t];
    }
    {   // reduce kv partials for 4 c-rows
#pragma unroll
        for (int r = 0; r < 4; ++r) {
            float acc = 0.f;
            for (int ch = 0; ch < KVCH; ++ch)
                acc += kvp[(((long)(h * KVCH + ch) * 128) + c0 + r) * 128 + t];
            kvr[r][t] = acc;
        }
    }
    for (int i = t; i < 256; i += 128) {   // ksum partial stage
        const int r = i >> 6, ch = i & 63;
        shks[r][ch] = ksp[(h * KVCH + ch) * 128 + c0 + r];
    }
    __syncthreads();
    if (t < 4) {
        float s = 0.f;
#pragma unroll
        for (int ch = 0; ch < 64; ++ch) s += shks[t][ch];
        ksum[h * 128 + c0 + t] = s;
    }
    float m[4] = {0.f, 0.f, 0.f, 0.f};
#pragma unroll 4
    for (int d = 0; d < 128; ++d) {
        const float wv = wt[d][t];
#pragma unroll
        for (int r = 0; r < 4; ++r) m[r] += kvr[r][d] * wv;
    }
    // lane t owns Mt[e=t][c0..c0+3] -> one 8B store
    bf16x4 pk;
#pragma unroll
    for (int r = 0; r < 4; ++r) pk[r] = (__bf16)m[r];
    *(bf16x4*)(Mt + ((long)(h * 128 + t)) * 128 + c0) = pk;
}

// ---------------- linear apply (MFMA) + sparse merge: writes d_out, runs LAST ----------------
__global__ __launch_bounds__(256) void k_linear(const float* __restrict__ q,
                                                const __bf16* __restrict__ Mt,
                                                const float* __restrict__ ksum,
                                                const float* __restrict__ bproj,
                                                const float* __restrict__ Osp,
                                                const float* __restrict__ lsp,
                                                float* __restrict__ out)
{
    __shared__ __align__(16) __bf16 fq[128 * 136];   // raw exp, stride 136
    __shared__ float dinv[128];
    __shared__ float dsp[128];
    const int qb = blockIdx.x, h = blockIdx.y, t = threadIdx.x;
    const int l0 = qb * 128;

    {   // phase 1: per-row raw-exp + fused denominator; 2 threads/row
        const int row = t >> 1, half = t & 1;
        const float* qrow = q + ((long)((l0 + row) * NH + h)) * DH + half * 64;
        float vals[64];
#pragma unroll
        for (int j = 0; j < 16; ++j) {
            float4 x = ((const float4*)qrow)[j];
            vals[4*j] = x.x; vals[4*j+1] = x.y; vals[4*j+2] = x.z; vals[4*j+3] = x.w;
        }
        float mx = -__builtin_inff();
#pragma unroll
        for (int c = 0; c < 64; ++c) mx = fmaxf(mx, vals[c]);
        mx = fmaxf(mx, __shfl_xor(mx, 1));
        float sm = 0.f, dk = 0.f;
        const float* ks = ksum + h * DH + half * 64;
#pragma unroll
        for (int c = 0; c < 64; ++c) {
            float e = __expf(vals[c] - mx);
            vals[c] = e; sm += e; dk += e * ks[c];
        }
        __bf16* dst = fq + row * 136 + half * 64;
#pragma unroll
        for (int g = 0; g < 8; ++g) {
            bf16x8 o;
#pragma unroll
            for (int e2 = 0; e2 < 8; ++e2) o[e2] = (__bf16)vals[g * 8 + e2];
            *(bf16x8*)(dst + g * 8) = o;
        }
        sm += __shfl_xor(sm, 1);
        dk += __shfl_xor(dk, 1);
        if (half == 0) dinv[row] = 1.f / (1e-5f * sm + dk);
    }
    if (t < 128) {
        const long p0 = ((long)(h * NQB + qb)) * 128 + t;
        const long p1 = ((long)((NH + h) * NQB + qb)) * 128 + t;
        dsp[t] = 1.f / (lsp[p0] + lsp[p1]);
    }
    __syncthreads();

    // phase 2: MFMA  [128 rows x 128 e], wave w owns rows w*32..+32
    const int w = t >> 6, lane = t & 63, l16 = lane & 15, quad = lane >> 4;
    const __bf16* Bh = Mt + (long)h * DH * DH;
    const floatx4 vzero = {0.f, 0.f, 0.f, 0.f};
    floatx4 acc[2][8];
#pragma unroll
    for (int mt = 0; mt < 2; ++mt)
#pragma unroll
        for (int nt = 0; nt < 8; ++nt) acc[mt][nt] = vzero;
#pragma unroll
    for (int ksx = 0; ksx < 4; ++ksx) {
        bf16x8 af[2];
#pragma unroll
        for (int mt = 0; mt < 2; ++mt)
            af[mt] = *(const bf16x8*)(fq + (w * 32 + mt * 16 + l16) * 136 + ksx * 32 + quad * 8);
#pragma unroll
        for (int nt = 0; nt < 8; ++nt) {
            bf16x8 bf = *(const bf16x8*)(Bh + ((long)(nt * 16 + l16)) * DH + ksx * 32 + quad * 8);
#pragma unroll
            for (int mt = 0; mt < 2; ++mt)
                acc[mt][nt] = __builtin_amdgcn_mfma_f32_16x16x32_bf16(af[mt], bf, acc[mt][nt], 0, 0, 0);
        }
    }

    // epilogue: denom, bias, sparse merge
    float bias[8];
#pragma unroll
    for (int nt = 0; nt < 8; ++nt) bias[nt] = bproj[nt * 16 + l16];
    const float* O0b = Osp + (((long)(h * NQB + qb)) * 128) * 128;
    const float* O1b = Osp + (((long)((NH + h) * NQB + qb)) * 128) * 128;
#pragma unroll
    for (int mt = 0; mt < 2; ++mt) {
#pragma unroll
        for (int r = 0; r < 4; ++r) {
            const int row = w * 32 + mt * 16 + quad * 4 + r;
            const float di = dinv[row], ds = dsp[row];
            float* op = out + ((long)((l0 + row) * NH + h)) * DH;
            const float* o0 = O0b + (long)row * 128;
            const float* o1 = O1b + (long)row * 128;
#pragma unroll
            for (int nt = 0; nt < 8; ++nt) {
                const int e = nt * 16 + l16;
                op[e] = acc[mt][nt][r] * di + bias[nt] + (o0[e] + o1[e]) * ds;
            }
        }
    }
}

// ---------------- sparse flash attention: EXACT round-3 body (verified, 58.5 us, absmax 0.0029).
// ---------------- Swapped QK^T (S^T = K·Q^T), register-P via permlane32_swap + shfl_xor(16),
// ---------------- double-buffered K/V LDS, one barrier/iter. Scale applied in fp32 at exp
// ---------------- (scale-fold into bf16 Q REVERTED: r6 failed correctness 0.053 — unexplained,
// ---------------- do not re-attempt without isolating the mechanism).
#define SM_K0   0
#define SM_K1   17408
#define SM_V0   34816
#define SM_V1   53248
#define SM_LUT  71680
#define SM_SZ   71744

static __device__ __forceinline__ unsigned int pack_bf16x2(float lo, float hi)
{
    union { __bf16 h[2]; unsigned int u; } cv;
    cv.h[0] = (__bf16)lo; cv.h[1] = (__bf16)hi;
    return cv.u;
}

__global__ __launch_bounds__(256, 2) void k_sparse(const float* __restrict__ q,
                                                   const __bf16* __restrict__ kb16,
                                                   const __bf16* __restrict__ vt16,
                                                   const int* __restrict__ lut,
                                                   float* __restrict__ Osp,
                                                   float* __restrict__ lsp)
{
    __shared__ __align__(16) char smem[SM_SZ];
    int* luts = (int*)(smem + SM_LUT);

    const int id = blockIdx.x;
    const int xcd = id & 7, slot = id >> 3;
    const int pair = xcd + 8 * (slot >> 5);   // 0..15
    const int qb = slot & 31;
    const int h = pair >> 1, kc = pair & 1;
    const int t = threadIdx.x;
    const int w = t >> 6;
    const int lane = t & 63;
    const int l16 = lane & 15;
    const int quad = lane >> 4;
    const bool qe = (quad & 1) == 0;          // quad even?

    if (t < 16) luts[t] = lut[(h * NQB + qb) * TOPK + kc * 16 + t];

    bf16x8 qf[2][4];
#pragma unroll
    for (int mt = 0; mt < 2; ++mt) {
        const int gl = qb * 128 + w * 32 + mt * 16 + l16;
        const float* qrow = q + ((long)(gl * NH + h)) * DH;
#pragma unroll
        for (int ks = 0; ks < 4; ++ks) {
            const float4* s2 = (const float4*)(qrow + ks * 32 + quad * 8);
            float4 a = s2[0], b = s2[1];
            bf16x8 f;
            f[0] = (__bf16)a.x; f[1] = (__bf16)a.y; f[2] = (__bf16)a.z; f[3] = (__bf16)a.w;
            f[4] = (__bf16)b.x; f[5] = (__bf16)b.y; f[6] = (__bf16)b.z; f[7] = (__bf16)b.w;
            qf[mt][ks] = f;
        }
    }

    const floatx4 vzero = {0.f, 0.f, 0.f, 0.f};
    floatx4 o_acc[2][8];
#pragma unroll
    for (int mt = 0; mt < 2; ++mt)
#pragma unroll
        for (int nt = 0; nt < 8; ++nt) o_acc[mt][nt] = vzero;
    float lsum2[2] = {0.f, 0.f};

    const float scale = 0.08838834764831845f;
    const __bf16* kbh = kb16 + (long)h * L_SEQ * DH;
    const __bf16* vth = vt16 + (long)h * DH * L_SEQ;
    int kr[4], kc8[4], vr[4], vc8[4];
#pragma unroll
    for (int j = 0; j < 4; ++j) {
        const int si = t + j * 256;
        kr[j] = si >> 4; kc8[j] = si & 15;
        vr[j] = si >> 3; vc8[j] = si & 7;
    }

    __syncthreads();   // luts ready

    // prologue: tile0 -> buf0; prefetch tile1 -> regs
    {
        const int b0 = luts[0];
        __bf16* K0 = (__bf16*)(smem + SM_K0);
        __bf16* V0 = (__bf16*)(smem + SM_V0);
#pragma unroll
        for (int j = 0; j < 4; ++j) {
            bf16x8 kk = *(const bf16x8*)(kbh + ((long)(b0 * 64 + kr[j])) * DH + kc8[j] * 8);
            bf16x8 vv = *(const bf16x8*)(vth + (long)vr[j] * L_SEQ + b0 * 64 + vc8[j] * 8);
            *(bf16x8*)(K0 + kr[j] * 136 + kc8[j] * 8) = kk;
            *(bf16x8*)(V0 + vr[j] * 72 + vc8[j] * 8)  = vv;
        }
    }
    bf16x8 pk[4], pv[4];
    {
        const int b1 = luts[1];
#pragma unroll
        for (int j = 0; j < 4; ++j) {
            pk[j] = *(const bf16x8*)(kbh + ((long)(b1 * 64 + kr[j])) * DH + kc8[j] * 8);
            pv[j] = *(const bf16x8*)(vth + (long)vr[j] * L_SEQ + b1 * 64 + vc8[j] * 8);
        }
    }
    __syncthreads();   // buf0 ready

    for (int it = 0; it < 16; ++it) {
        const int cur = it & 1;
        const __bf16* Kc = (const __bf16*)(smem + (cur ? SM_K1 : SM_K0));
        const __bf16* Vc = (const __bf16*)(smem + (cur ? SM_V1 : SM_V0));

        if (it < 15) {   // write tile it+1 (regs) -> other buffer
            __bf16* Kn = (__bf16*)(smem + (cur ? SM_K0 : SM_K1));
            __bf16* Vn = (__bf16*)(smem + (cur ? SM_V0 : SM_V1));
#pragma unroll
            for (int j = 0; j < 4; ++j) {
                *(bf16x8*)(Kn + kr[j] * 136 + kc8[j] * 8) = pk[j];
                *(bf16x8*)(Vn + vr[j] * 72 + vc8[j] * 8)  = pv[j];
            }
        }
        if (it < 14) {   // prefetch tile it+2 -> regs
            const int b2 = luts[it + 2];
#pragma unroll
            for (int j = 0; j < 4; ++j) {
                pk[j] = *(const bf16x8*)(kbh + ((long)(b2 * 64 + kr[j])) * DH + kc8[j] * 8);
                pv[j] = *(const bf16x8*)(vth + (long)vr[j] * L_SEQ + b2 * 64 + vc8[j] * 8);
            }
        }

        // swapped QK^T: sfr[mt][nt][r] = S[q = mt*16 + l16][k = nt*16 + quad*4 + r]
        floatx4 sfr[2][4];
#pragma unroll
        for (int mt = 0; mt < 2; ++mt)
#pragma unroll
            for (int nt = 0; nt < 4; ++nt) sfr[mt][nt] = vzero;
#pragma unroll
        for (int ks = 0; ks < 4; ++ks) {
            bf16x8 bf[4];
#pragma unroll
            for (int nt = 0; nt < 4; ++nt)
                bf[nt] = *(const bf16x8*)(Kc + (nt * 16 + l16) * 136 + ks * 32 + quad * 8);
#pragma unroll
            for (int mt = 0; mt < 2; ++mt)
#pragma unroll
                for (int nt = 0; nt < 4; ++nt)
                    sfr[mt][nt] = __builtin_amdgcn_mfma_f32_16x16x32_bf16(bf[nt], qf[mt][ks], sfr[mt][nt], 0, 0, 0);
        }

        // exp + pack to bf16 pair-words: pw[mt][nt][0]=(r0,r1), [1]=(r2,r3)
        unsigned int pw[2][4][2];
#pragma unroll
        for (int mt = 0; mt < 2; ++mt) {
#pragma unroll
            for (int nt = 0; nt < 4; ++nt) {
                float p0 = __expf(sfr[mt][nt][0] * scale);
                float p1 = __expf(sfr[mt][nt][1] * scale);
                float p2 = __expf(sfr[mt][nt][2] * scale);
                float p3 = __expf(sfr[mt][nt][3] * scale);
                lsum2[mt] += (p0 + p1) + (p2 + p3);
                pw[mt][nt][0] = pack_bf16x2(p0, p1);
                pw[mt][nt][1] = pack_bf16x2(p2, p3);
            }
        }

        // in-register transpose: build PV A-frags afr[mt][ks2] (k = ks2*32 + quad*8 + j)
        bf16x8 afr[2][2];
#pragma unroll
        for (int mt = 0; mt < 2; ++mt) {
#pragma unroll
            for (int ks2 = 0; ks2 < 2; ++ks2) {
                unsigned int P0 = pw[mt][ks2 * 2][0],     P1 = pw[mt][ks2 * 2][1];
                unsigned int Q0 = pw[mt][ks2 * 2 + 1][0], Q1 = pw[mt][ks2 * 2 + 1][1];
                asm("v_permlane32_swap_b32 %0, %1" : "+v"(P0), "+v"(Q0));
                asm("v_permlane32_swap_b32 %0, %1" : "+v"(P1), "+v"(Q1));
                unsigned int Px0 = __shfl_xor(P0, 16), Qx0 = __shfl_xor(Q0, 16);
                unsigned int Px1 = __shfl_xor(P1, 16), Qx1 = __shfl_xor(Q1, 16);
                union { unsigned int u[4]; bf16x8 v; } cv;
                cv.u[0] = qe ? P0  : Qx0;
                cv.u[1] = qe ? P1  : Qx1;
                cv.u[2] = qe ? Px0 : Q0;
                cv.u[3] = qe ? Px1 : Q1;
                afr[mt][ks2] = cv.v;
            }
        }

        // PV: O += P · V
#pragma unroll
        for (int ks2 = 0; ks2 < 2; ++ks2) {
#pragma unroll
            for (int nt = 0; nt < 8; ++nt) {
                bf16x8 bv = *(const bf16x8*)(Vc + (nt * 16 + l16) * 72 + ks2 * 32 + quad * 8);
#pragma unroll
                for (int mt = 0; mt < 2; ++mt)
                    o_acc[mt][nt] = __builtin_amdgcn_mfma_f32_16x16x32_bf16(afr[mt][ks2], bv, o_acc[mt][nt], 0, 0, 0);
            }
        }
        __syncthreads();   // single barrier per iteration
    }

    const long pbase = (((long)(kc * NH + h) * NQB + qb)) * 128;
#pragma unroll
    for (int mt = 0; mt < 2; ++mt) {
        lsum2[mt] += __shfl_xor(lsum2[mt], 16);
        lsum2[mt] += __shfl_xor(lsum2[mt], 32);
        if (quad == 0) lsp[pbase + w * 32 + mt * 16 + l16] = lsum2[mt];
    }
#pragma unroll
    for (int mt = 0; mt < 2; ++mt) {
#pragma unroll
        for (int r = 0; r < 4; ++r) {
            const int row = w * 32 + mt * 16 + quad * 4 + r;
            float* od = Osp + (pbase + row) * 128;
#pragma unroll
            for (int nt = 0; nt < 8; ++nt)
                od[nt * 16 + l16] = o_acc[mt][nt][r];
        }
    }
}

extern "C" void kernel_launch(void* const* d_in, const int* in_sizes, int n_in,
                              void* d_out, int out_size, void* d_ws, size_t ws_size,
                              hipStream_t stream)
{
    const float* q = (const float*)d_in[0];
    const float* k = (const float*)d_in[1];
    const float* v = (const float*)d_in[2];
    const float* w = (const float*)d_in[3];
    const float* b = (const float*)d_in[4];
    float* out = (float*)d_out;
    char* ws = (char*)d_ws;

    __bf16* kb16 = (__bf16*)(ws + 0);          //  8,388,608  K bf16 [h][l][d]
    __bf16* vt16 = (__bf16*)(ws + 8388608);    //  8,388,608  V bf16 [h][d][l]
    float*  Osp  = (float*)(ws + 16777216);    // 33,554,432  sparse O partials [kc][h][qb][row][e]
    float*  kvp  = (float*)(ws + 16777216);    // 33,554,432  (alias) kv partials [h][ch][c][d]
    float*  lsp  = (float*)(ws + 50331648);    //    262,144  sparse l partials
    float*  pks  = (float*)(ws + 50593792);    //    262,144
    int*    lut  = (int*)  (ws + 50855936);    //     32,768
    float*  ksp  = (float*)(ws + 50888704);    //    262,144  ksum partials (64 chunks)
    float*  ksum = (float*)(ws + 51150848);    //      4,096
    __bf16* Mt   = (__bf16*)(ws + 51154944);   //    262,144  (kv @ W^T)^T bf16 [h][e][c]

    k_prep    <<<dim3(64, 8),   dim3(256), 0, stream>>>(k, v, kb16, vt16, pks, kvp, ksp);
    k_route   <<<dim3(32, 8),   dim3(256), 0, stream>>>(q, pks, lut);
    k_reduce_m<<<dim3(32, 8),   dim3(128), 0, stream>>>(kvp, ksp, w, Mt, ksum);
    k_sparse  <<<dim3(512),     dim3(256), 0, stream>>>(q, kb16, vt16, lut, Osp, lsp);
    k_linear  <<<dim3(32, 8),   dim3(256), 0, stream>>>(q, Mt, ksum, b, Osp, lsp, out); // writes d_out
}